// Round 1
// baseline (165.211 us; speedup 1.0000x reference)
//
#include <hip/hip_runtime.h>

// GCN-style symmetric-normalized CSR aggregation.
// out[d][f] = sum_{e in [row_ptr[d], row_ptr[d+1])} feat[col_idx[e]][f] * rsqrt(deg[d]*deg[col_idx[e]])
//
// Mapping: one wave (64 lanes) per destination row.
//   - 4 lane-groups of 16 lanes; group g handles edges start+g, start+g+4, ...
//   - within a group, lane k loads float4 at feature offset 4k (16 lanes x 16B = 256B row, coalesced)
//   - cross-group reduction with __shfl_xor(16), __shfl_xor(32); groups 0 lanes store.

#define GCN_FEAT 64

__global__ __launch_bounds__(256) void gcn_csr_agg(
    const int* __restrict__ row_ptr,
    const int* __restrict__ col_idx,
    const float* __restrict__ feat,
    const float* __restrict__ deg,
    float* __restrict__ out,
    int n_nodes)
{
    const int gtid = blockIdx.x * blockDim.x + threadIdx.x;
    const int row  = gtid >> 6;          // wave id = destination node
    if (row >= n_nodes) return;
    const int lane = threadIdx.x & 63;
    const int sub  = lane >> 4;          // edge slot 0..3 within wave
    const int fcol = (lane & 15) << 2;   // feature offset 0,4,...,60

    const int start = row_ptr[row];
    const int end   = row_ptr[row + 1];
    const float dinv = rsqrtf(deg[row]); // deg clamped >= 1 by setup

    float4 acc = make_float4(0.f, 0.f, 0.f, 0.f);

    for (int eb = start; eb < end; eb += 4) {
        const int e = eb + sub;
        if (e < end) {
            const int s = col_idx[e];                    // broadcast within lane-group
            const float w = dinv * rsqrtf(deg[s]);       // broadcast within lane-group
            const float4 f = *reinterpret_cast<const float4*>(
                feat + ((long long)s << 6) + fcol);      // 16B/lane, coalesced 256B per edge
            acc.x += w * f.x;
            acc.y += w * f.y;
            acc.z += w * f.z;
            acc.w += w * f.w;
        }
    }

    // Reduce across the 4 edge slots (lanes differing in bits 4 and 5).
    acc.x += __shfl_xor(acc.x, 16); acc.y += __shfl_xor(acc.y, 16);
    acc.z += __shfl_xor(acc.z, 16); acc.w += __shfl_xor(acc.w, 16);
    acc.x += __shfl_xor(acc.x, 32); acc.y += __shfl_xor(acc.y, 32);
    acc.z += __shfl_xor(acc.z, 32); acc.w += __shfl_xor(acc.w, 32);

    if (sub == 0) {
        *reinterpret_cast<float4*>(out + ((long long)row << 6) + fcol) = acc;
    }
}

extern "C" void kernel_launch(void* const* d_in, const int* in_sizes, int n_in,
                              void* d_out, int out_size, void* d_ws, size_t ws_size,
                              hipStream_t stream) {
    const int*   row_ptr = (const int*)d_in[0];
    const int*   col_idx = (const int*)d_in[1];
    const float* feat    = (const float*)d_in[2];
    const float* deg     = (const float*)d_in[3];
    float*       out     = (float*)d_out;

    const int n_nodes = in_sizes[0] - 1;     // row_ptr has n_nodes+1 entries
    const long long threads = (long long)n_nodes * 64;
    const int block = 256;
    const int grid  = (int)((threads + block - 1) / block);

    gcn_csr_agg<<<grid, block, 0, stream>>>(row_ptr, col_idx, feat, deg, out, n_nodes);
}

// Round 3
// 138.033 us; speedup vs baseline: 1.1969x; 1.1969x over previous
//
#include <hip/hip_runtime.h>

// GCN-style symmetric-normalized CSR aggregation.
// out[d][f] = sum_{e in [row_ptr[d], row_ptr[d+1])} feat[col_idx[e]][f] * rsqrt(deg[d]*deg[col_idx[e]])
//
// Mapping: one wave (64 lanes) per destination row.
//   - 4 lane-groups of 16 lanes = 4 edge slots; 4-way unrolled => 16 edges in
//     flight per iteration (avg degree is 16 -> typical row = ONE iteration).
//   - within a group, lane k loads float4 at feature offset 4k (16 lanes x 16B
//     = full 256B row, coalesced).
//   - out-of-range slots clamp to the row's last edge (duplicate address -> L1
//     hit) with weight 0: branchless, all loads issue for max MLP.
//   - cross-group reduction with __shfl_xor(16/32); group-0 lanes store (nt).

typedef float v4f __attribute__((ext_vector_type(4)));  // native vector: ok for nontemporal builtin

__global__ __launch_bounds__(256) void gcn_csr_agg(
    const int* __restrict__ row_ptr,
    const int* __restrict__ col_idx,
    const float* __restrict__ feat,
    const float* __restrict__ deg,
    float* __restrict__ out,
    int n_nodes)
{
    const int gtid = blockIdx.x * blockDim.x + threadIdx.x;
    const int row  = gtid >> 6;          // wave id = destination node
    if (row >= n_nodes) return;
    const int lane = threadIdx.x & 63;
    const int sub  = lane >> 4;          // edge slot 0..3 within wave
    const int fcol = (lane & 15) << 2;   // feature offset 0,4,...,60

    const int start = row_ptr[row];
    const int end   = row_ptr[row + 1];
    const int last  = end - 1;
    const float dinv = rsqrtf(deg[row]); // deg clamped >= 1 by setup

    v4f acc = {0.f, 0.f, 0.f, 0.f};

    for (int eb = start; eb < end; eb += 16) {
        const int e0 = eb + sub;
        const int e1 = e0 + 4;
        const int e2 = e0 + 8;
        const int e3 = e0 + 12;
        // Clamp: loop only runs if end > start, so last >= start >= 0.
        const int c0 = min(e0, last);
        const int c1 = min(e1, last);
        const int c2 = min(e2, last);
        const int c3 = min(e3, last);

        // Stage 1: all edge-index loads issue together.
        const int s0 = col_idx[c0];
        const int s1 = col_idx[c1];
        const int s2 = col_idx[c2];
        const int s3 = col_idx[c3];

        // Stage 2: all degree + feature loads issue together (16 float4
        // gathers in flight per wave).
        const float d0 = deg[s0];
        const float d1 = deg[s1];
        const float d2 = deg[s2];
        const float d3 = deg[s3];
        const v4f f0 = *reinterpret_cast<const v4f*>(feat + ((long long)s0 << 6) + fcol);
        const v4f f1 = *reinterpret_cast<const v4f*>(feat + ((long long)s1 << 6) + fcol);
        const v4f f2 = *reinterpret_cast<const v4f*>(feat + ((long long)s2 << 6) + fcol);
        const v4f f3 = *reinterpret_cast<const v4f*>(feat + ((long long)s3 << 6) + fcol);

        // Stage 3: weights (0 for clamped duplicate slots) + accumulate.
        const float w0 = (e0 <= last) ? dinv * rsqrtf(d0) : 0.f;
        const float w1 = (e1 <= last) ? dinv * rsqrtf(d1) : 0.f;
        const float w2 = (e2 <= last) ? dinv * rsqrtf(d2) : 0.f;
        const float w3 = (e3 <= last) ? dinv * rsqrtf(d3) : 0.f;

        acc += w0 * f0 + w1 * f1 + w2 * f2 + w3 * f3;
    }

    // Reduce across the 4 edge slots (lanes differing in bits 4 and 5).
    acc.x += __shfl_xor(acc.x, 16); acc.y += __shfl_xor(acc.y, 16);
    acc.z += __shfl_xor(acc.z, 16); acc.w += __shfl_xor(acc.w, 16);
    acc.x += __shfl_xor(acc.x, 32); acc.y += __shfl_xor(acc.y, 32);
    acc.z += __shfl_xor(acc.z, 32); acc.w += __shfl_xor(acc.w, 32);

    if (sub == 0) {
        v4f* po = reinterpret_cast<v4f*>(out + ((long long)row << 6) + fcol);
        __builtin_nontemporal_store(acc, po);  // out is write-once: don't pollute L2
    }
}

extern "C" void kernel_launch(void* const* d_in, const int* in_sizes, int n_in,
                              void* d_out, int out_size, void* d_ws, size_t ws_size,
                              hipStream_t stream) {
    const int*   row_ptr = (const int*)d_in[0];
    const int*   col_idx = (const int*)d_in[1];
    const float* feat    = (const float*)d_in[2];
    const float* deg     = (const float*)d_in[3];
    float*       out     = (float*)d_out;

    const int n_nodes = in_sizes[0] - 1;     // row_ptr has n_nodes+1 entries
    const long long threads = (long long)n_nodes * 64;
    const int block = 256;
    const int grid  = (int)((threads + block - 1) / block);

    gcn_csr_agg<<<grid, block, 0, stream>>>(row_ptr, col_idx, feat, deg, out, n_nodes);
}